// Round 1
// baseline (75.079 us; speedup 1.0000x reference)
//
#include <hip/hip_runtime.h>
#include <math.h>

// Collapsed computation:
//   psi1 = U1[:,0]  (32 complex)          -- from params1 circuit
//   r0 = U2[0,:], r1 = U2[1,:]            -- from params2 circuit
//   fin0 = sum_{i,j} O[i,j] * r0[i]*psi1[j],  fin1 likewise
//   x = |fin0|^2 + |fin1|^2 ; out = [x, 1-x]
// => four fixed real 32x32 coefficient matrices (Re/Im of outer products),
//    per batch: four 1024-long real dot products against O. Memory-bound.

__device__ float g_coef[4096];  // [c=0..3][lane=0..63][k=0..3][m=0..3] as float4s

__device__ __forceinline__ void apply_ry(float c, float s, int mask, int lane,
                                         float& re, float& im) {
    float pre = __shfl_xor(re, mask, 64);
    float pim = __shfl_xor(im, mask, 64);
    float sg = (lane & mask) ? s : -s;
    re = c * re + sg * pre;
    im = c * im + sg * pim;
}

__device__ __forceinline__ void apply_rx(float c, float s, int mask,
                                         float& re, float& im) {
    float pre = __shfl_xor(re, mask, 64);
    float pim = __shfl_xor(im, mask, 64);
    float nre = c * re + s * pim;   // psi' = c*psi - i*s*psi_partner
    float nim = c * im - s * pre;
    re = nre; im = nim;
}

__device__ __forceinline__ void apply_cnot(int cmask, int tmask, int lane,
                                           float& re, float& im) {
    float pre = __shfl_xor(re, tmask, 64);
    float pim = __shfl_xor(im, tmask, 64);
    if (lane & cmask) { re = pre; im = pim; }
}

// One wave. Lane = basis state index (lanes 32..63 mirror 0..31 harmlessly:
// all shfl masks are <= 16 so the halves never mix).
__global__ void setup_kernel(const float* __restrict__ p1,
                             const float* __restrict__ p2) {
    const int lane = threadIdx.x;
    const int l5 = lane & 31;
    __shared__ float sh[6][32];  // psi_re, psi_im, r0_re, r0_im, r1_re, r1_im

    // ---- psi1 = U1 @ e0 : forward circuit, params1 (5 blocks, wires 0..4)
    float re = (l5 == 0) ? 1.f : 0.f, im = 0.f;
    for (int b = 0; b < 5; ++b) {
        for (int w = 0; w < 5; ++w) {
            float th = p1[b * 10 + w] * 0.5f;
            apply_ry(cosf(th), sinf(th), 1 << (4 - w), lane, re, im);
        }
        for (int w = 0; w < 5; ++w) {
            float th = p1[b * 10 + 5 + w] * 0.5f;
            apply_rx(cosf(th), sinf(th), 1 << (4 - w), re, im);
        }
        for (int t = 0; t < 5; ++t)
            if (t != b) apply_cnot(1 << (4 - b), 1 << (4 - t), lane, re, im);
    }
    if (lane < 32) { sh[0][lane] = re; sh[1][lane] = im; }

    // ---- rows r of U2: r^T = U2^T e_r = reversed circuit with transposed
    // gates (RY^T = RY(-th), RX^T = RX, CNOT^T = CNOT). params2: 4 blocks, wires 0..3.
    for (int r = 0; r < 2; ++r) {
        re = (l5 == r) ? 1.f : 0.f; im = 0.f;
        for (int b = 3; b >= 0; --b) {
            for (int t = 3; t >= 0; --t)
                if (t != b) apply_cnot(1 << (4 - b), 1 << (4 - t), lane, re, im);
            for (int w = 0; w < 4; ++w) {
                float th = p2[b * 8 + 4 + w] * 0.5f;
                apply_rx(cosf(th), sinf(th), 1 << (4 - w), re, im);
            }
            for (int w = 0; w < 4; ++w) {
                float th = p2[b * 8 + w] * 0.5f;
                apply_ry(cosf(th), -sinf(th), 1 << (4 - w), lane, re, im);
            }
        }
        if (lane < 32) { sh[2 + 2 * r][lane] = re; sh[3 + 2 * r][lane] = im; }
    }
    __syncthreads();

    // ---- coefficient table: element e = 256*c + 4*lane + k maps to O[i,j],
    // i = e>>5 (row), j = e&31 (col). float4 = {ReW0, ImW0, ReW1, ImW1}.
    for (int c = 0; c < 4; ++c) {
        for (int k = 0; k < 4; ++k) {
            int e = 256 * c + 4 * lane + k;
            int i = e >> 5, j = e & 31;
            float pr = sh[0][j], pi = sh[1][j];
            float ar = sh[2][i], ai = sh[3][i];
            float br = sh[4][i], bi = sh[5][i];
            float4 v;
            v.x = ar * pr - ai * pi;
            v.y = ar * pi + ai * pr;
            v.z = br * pr - bi * pi;
            v.w = br * pi + bi * pr;
            ((float4*)g_coef)[c * 256 + lane * 4 + k] = v;
        }
    }
}

// One wave per batch (grid-stride). Lane l owns elements 256c + 4l + k
// (c=0..3, k=0..3): each wave-level float4 load covers a contiguous 1 KB.
__global__ __launch_bounds__(256) void oracle_kernel(const float* __restrict__ O,
                                                     float* __restrict__ out,
                                                     int nbatch) {
    const int lane = threadIdx.x & 63;
    const int wid = blockIdx.x * (blockDim.x >> 6) + (threadIdx.x >> 6);
    const int nw = gridDim.x * (blockDim.x >> 6);

    float4 cf[4][4];
    const float4* cp = (const float4*)g_coef;
#pragma unroll
    for (int c = 0; c < 4; ++c)
#pragma unroll
        for (int k = 0; k < 4; ++k) cf[c][k] = cp[c * 256 + lane * 4 + k];

    for (int b = wid; b < nbatch; b += nw) {
        const float4* row = (const float4*)(O + (size_t)b * 1024);
        float a0 = 0.f, a1 = 0.f, a2 = 0.f, a3 = 0.f;
#pragma unroll
        for (int c = 0; c < 4; ++c) {
            float4 o = row[c * 64 + lane];
            a0 += o.x * cf[c][0].x + o.y * cf[c][1].x + o.z * cf[c][2].x + o.w * cf[c][3].x;
            a1 += o.x * cf[c][0].y + o.y * cf[c][1].y + o.z * cf[c][2].y + o.w * cf[c][3].y;
            a2 += o.x * cf[c][0].z + o.y * cf[c][1].z + o.z * cf[c][2].z + o.w * cf[c][3].z;
            a3 += o.x * cf[c][0].w + o.y * cf[c][1].w + o.z * cf[c][2].w + o.w * cf[c][3].w;
        }
#pragma unroll
        for (int m = 1; m < 64; m <<= 1) {
            a0 += __shfl_xor(a0, m, 64);
            a1 += __shfl_xor(a1, m, 64);
            a2 += __shfl_xor(a2, m, 64);
            a3 += __shfl_xor(a3, m, 64);
        }
        if (lane == 0) {
            float x = a0 * a0 + a1 * a1 + a2 * a2 + a3 * a3;
            ((float2*)out)[b] = make_float2(x, 1.0f - x);
        }
    }
}

extern "C" void kernel_launch(void* const* d_in, const int* in_sizes, int n_in,
                              void* d_out, int out_size, void* d_ws, size_t ws_size,
                              hipStream_t stream) {
    const float* oracles = (const float*)d_in[0];
    const float* p1 = (const float*)d_in[1];
    const float* p2 = (const float*)d_in[2];
    float* out = (float*)d_out;
    int nbatch = in_sizes[0] / 1024;

    setup_kernel<<<1, 64, 0, stream>>>(p1, p2);
    oracle_kernel<<<2048, 256, 0, stream>>>(oracles, out, nbatch);
}

// Round 2
// 54.111 us; speedup vs baseline: 1.3875x; 1.3875x over previous
//
#include <hip/hip_runtime.h>
#include <math.h>

// Collapsed computation:
//   psi1 = U1[:,0]  (32 complex)          -- from params1 circuit
//   r0 = U2[0,:], r1 = U2[1,:]            -- from params2 circuit
//   fin0 = sum_{i,j} O[i,j] * r0[i]*psi1[j],  fin1 likewise
//   x = |fin0|^2 + |fin1|^2 ; out = [x, 1-x]
// => four fixed real 32x32 coefficient matrices (Re/Im of outer products),
//    per batch: four 1024-long real dot products against O. Memory-bound:
//    268 MB read once, ~0.5 GFLOP total -> HBM roofline ~40 us.

__device__ float g_coef[4096];  // [c=0..3][lane=0..63][k=0..3][m=0..3] as float4s

__device__ __forceinline__ void apply_ry(float c, float s, int mask, int lane,
                                         float& re, float& im) {
    float pre = __shfl_xor(re, mask, 64);
    float pim = __shfl_xor(im, mask, 64);
    float sg = (lane & mask) ? s : -s;
    re = c * re + sg * pre;
    im = c * im + sg * pim;
}

__device__ __forceinline__ void apply_rx(float c, float s, int mask,
                                         float& re, float& im) {
    float pre = __shfl_xor(re, mask, 64);
    float pim = __shfl_xor(im, mask, 64);
    float nre = c * re + s * pim;   // psi' = c*psi - i*s*psi_partner
    float nim = c * im - s * pre;
    re = nre; im = nim;
}

__device__ __forceinline__ void apply_cnot(int cmask, int tmask, int lane,
                                           float& re, float& im) {
    float pre = __shfl_xor(re, tmask, 64);
    float pim = __shfl_xor(im, tmask, 64);
    if (lane & cmask) { re = pre; im = pim; }
}

// One wave. Lane = basis state index (lanes 32..63 mirror 0..31 harmlessly:
// all shfl masks are <= 16 so the halves never mix).
__global__ void setup_kernel(const float* __restrict__ p1,
                             const float* __restrict__ p2) {
    const int lane = threadIdx.x;
    const int l5 = lane & 31;
    __shared__ float sh[6][32];  // psi_re, psi_im, r0_re, r0_im, r1_re, r1_im

    // ---- psi1 = U1 @ e0 : forward circuit, params1 (5 blocks, wires 0..4)
    float re = (l5 == 0) ? 1.f : 0.f, im = 0.f;
    for (int b = 0; b < 5; ++b) {
        for (int w = 0; w < 5; ++w) {
            float s, c; __sincosf(p1[b * 10 + w] * 0.5f, &s, &c);
            apply_ry(c, s, 1 << (4 - w), lane, re, im);
        }
        for (int w = 0; w < 5; ++w) {
            float s, c; __sincosf(p1[b * 10 + 5 + w] * 0.5f, &s, &c);
            apply_rx(c, s, 1 << (4 - w), re, im);
        }
        for (int t = 0; t < 5; ++t)
            if (t != b) apply_cnot(1 << (4 - b), 1 << (4 - t), lane, re, im);
    }
    if (lane < 32) { sh[0][lane] = re; sh[1][lane] = im; }

    // ---- rows r of U2: r^T = U2^T e_r = reversed circuit with transposed
    // gates (RY^T = RY(-th), RX^T = RX, CNOT^T = CNOT). params2: 4 blocks, wires 0..3.
    for (int r = 0; r < 2; ++r) {
        re = (l5 == r) ? 1.f : 0.f; im = 0.f;
        for (int b = 3; b >= 0; --b) {
            for (int t = 3; t >= 0; --t)
                if (t != b) apply_cnot(1 << (4 - b), 1 << (4 - t), lane, re, im);
            for (int w = 0; w < 4; ++w) {
                float s, c; __sincosf(p2[b * 8 + 4 + w] * 0.5f, &s, &c);
                apply_rx(c, s, 1 << (4 - w), re, im);
            }
            for (int w = 0; w < 4; ++w) {
                float s, c; __sincosf(p2[b * 8 + w] * 0.5f, &s, &c);
                apply_ry(c, -s, 1 << (4 - w), lane, re, im);
            }
        }
        if (lane < 32) { sh[2 + 2 * r][lane] = re; sh[3 + 2 * r][lane] = im; }
    }
    __syncthreads();

    // ---- coefficient table: element e = 256*c + 4*lane + k maps to O[i,j],
    // i = e>>5 (row), j = e&31 (col). float4 = {ReW0, ImW0, ReW1, ImW1}.
    for (int c = 0; c < 4; ++c) {
        for (int k = 0; k < 4; ++k) {
            int e = 256 * c + 4 * lane + k;
            int i = e >> 5, j = e & 31;
            float pr = sh[0][j], pi = sh[1][j];
            float ar = sh[2][i], ai = sh[3][i];
            float br = sh[4][i], bi = sh[5][i];
            float4 v;
            v.x = ar * pr - ai * pi;
            v.y = ar * pi + ai * pr;
            v.z = br * pr - bi * pi;
            v.w = br * pi + bi * pr;
            ((float4*)g_coef)[c * 256 + lane * 4 + k] = v;
        }
    }
}

// One wave per 8 batches (grid-stride). Lane l owns elements 256c + 4l + k:
// each wave-level float4 load covers a contiguous 1 KB. Software-pipelined:
// next batch's 4 loads are issued before the current batch's reduction so
// HBM latency hides under the shuffle chain.
__global__ __launch_bounds__(256, 4) void oracle_kernel(const float* __restrict__ O,
                                                        float* __restrict__ out,
                                                        int nbatch) {
    const int lane = threadIdx.x & 63;
    const int wid = blockIdx.x * (blockDim.x >> 6) + (threadIdx.x >> 6);
    const int nw = gridDim.x * (blockDim.x >> 6);

    float4 cf[4][4];
    const float4* cp = (const float4*)g_coef;
#pragma unroll
    for (int c = 0; c < 4; ++c)
#pragma unroll
        for (int k = 0; k < 4; ++k) cf[c][k] = cp[c * 256 + lane * 4 + k];

    int b = wid;
    if (b >= nbatch) return;

    float4 cur[4];
    {
        const float4* row = (const float4*)(O + (size_t)b * 1024);
#pragma unroll
        for (int c = 0; c < 4; ++c) cur[c] = row[c * 64 + lane];
    }

    while (true) {
        const int nb = b + nw;
        const bool more = nb < nbatch;
        float4 nxt[4];
        if (more) {
            const float4* row = (const float4*)(O + (size_t)nb * 1024);
#pragma unroll
            for (int c = 0; c < 4; ++c) nxt[c] = row[c * 64 + lane];
        }

        float a0 = 0.f, a1 = 0.f, a2 = 0.f, a3 = 0.f;
#pragma unroll
        for (int c = 0; c < 4; ++c) {
            float4 o = cur[c];
            a0 += o.x * cf[c][0].x + o.y * cf[c][1].x + o.z * cf[c][2].x + o.w * cf[c][3].x;
            a1 += o.x * cf[c][0].y + o.y * cf[c][1].y + o.z * cf[c][2].y + o.w * cf[c][3].y;
            a2 += o.x * cf[c][0].z + o.y * cf[c][1].z + o.z * cf[c][2].z + o.w * cf[c][3].z;
            a3 += o.x * cf[c][0].w + o.y * cf[c][1].w + o.z * cf[c][2].w + o.w * cf[c][3].w;
        }

        // 9-shuffle reduction: fold 4 accumulators into one value indexed by
        // lane&3, butterfly masks 4..32, then square + 2-shuffle combine.
        float v01 = (lane & 1) ? a1 : a0;
        float o01 = (lane & 1) ? a0 : a1;
        v01 += __shfl_xor(o01, 1, 64);
        float v23 = (lane & 1) ? a3 : a2;
        float o23 = (lane & 1) ? a2 : a3;
        v23 += __shfl_xor(o23, 1, 64);
        float v = (lane & 2) ? v23 : v01;
        float o = (lane & 2) ? v01 : v23;
        v += __shfl_xor(o, 2, 64);
#pragma unroll
        for (int m = 4; m < 64; m <<= 1) v += __shfl_xor(v, m, 64);
        float t = v * v;
        t += __shfl_xor(t, 1, 64);
        t += __shfl_xor(t, 2, 64);
        if (lane == 0) ((float2*)out)[b] = make_float2(t, 1.0f - t);

        if (!more) break;
        b = nb;
#pragma unroll
        for (int c = 0; c < 4; ++c) cur[c] = nxt[c];
    }
}

extern "C" void kernel_launch(void* const* d_in, const int* in_sizes, int n_in,
                              void* d_out, int out_size, void* d_ws, size_t ws_size,
                              hipStream_t stream) {
    const float* oracles = (const float*)d_in[0];
    const float* p1 = (const float*)d_in[1];
    const float* p2 = (const float*)d_in[2];
    float* out = (float*)d_out;
    int nbatch = in_sizes[0] / 1024;

    setup_kernel<<<1, 64, 0, stream>>>(p1, p2);
    oracle_kernel<<<2048, 256, 0, stream>>>(oracles, out, nbatch);
}

// Round 3
// 51.160 us; speedup vs baseline: 1.4675x; 1.0577x over previous
//
#include <hip/hip_runtime.h>
#include <math.h>

// Collapsed computation:
//   psi1 = U1[:,0]  (32 complex)          -- from params1 circuit
//   r0 = U2[0,:], r1 = U2[1,:]            -- from params2 circuit
//   fin0 = sum_{i,j} O[i,j] * r0[i]*psi1[j],  fin1 likewise
//   x = |fin0|^2 + |fin1|^2 ; out = [x, 1-x]
// => four fixed real 32x32 coefficient matrices (Re/Im of outer products),
//    per batch: four 1024-long real dot products against O. Memory-bound:
//    268 MB read once -> HBM roofline ~40 us.
//
// Single fused kernel: every wave redundantly simulates the 32-state circuit
// (shfl butterflies, ~115 gates) AFTER issuing its first two batches' global
// loads, so the ~2 us gate chain hides under the first wave of HBM traffic.
// No second dispatch, no barrier, no LDS.

__device__ __forceinline__ void apply_ry(float c, float s, int mask, int lane,
                                         float& re, float& im) {
    float pre = __shfl_xor(re, mask, 64);
    float pim = __shfl_xor(im, mask, 64);
    float sg = (lane & mask) ? s : -s;
    re = c * re + sg * pre;
    im = c * im + sg * pim;
}

__device__ __forceinline__ void apply_rx(float c, float s, int mask,
                                         float& re, float& im) {
    float pre = __shfl_xor(re, mask, 64);
    float pim = __shfl_xor(im, mask, 64);
    float nre = c * re + s * pim;   // psi' = c*psi - i*s*psi_partner
    float nim = c * im - s * pre;
    re = nre; im = nim;
}

__device__ __forceinline__ void apply_cnot(int cmask, int tmask, int lane,
                                           float& re, float& im) {
    float pre = __shfl_xor(re, tmask, 64);
    float pim = __shfl_xor(im, tmask, 64);
    if (lane & cmask) { re = pre; im = pim; }
}

// row r of U2 as a state: U2^T e_r = reversed circuit with transposed gates
// (RY^T = RY(-th), RX^T = RX, CNOT^T = CNOT). params2: 4 blocks, wires 0..3.
__device__ __forceinline__ void u2row(const float* __restrict__ p2, int r,
                                      int lane, float& re, float& im) {
    re = ((lane & 31) == r) ? 1.f : 0.f;
    im = 0.f;
    for (int b = 3; b >= 0; --b) {
        for (int t = 3; t >= 0; --t)
            if (t != b) apply_cnot(1 << (4 - b), 1 << (4 - t), lane, re, im);
        for (int w = 0; w < 4; ++w) {
            float s, c; __sincosf(p2[b * 8 + 4 + w] * 0.5f, &s, &c);
            apply_rx(c, s, 1 << (4 - w), re, im);
        }
        for (int w = 0; w < 4; ++w) {
            float s, c; __sincosf(p2[b * 8 + w] * 0.5f, &s, &c);
            apply_ry(c, -s, 1 << (4 - w), lane, re, im);
        }
    }
}

// One wave per 16 batches (grid-stride). Lane l owns elements 256c + 4l + k:
// each wave-level float4 load covers a contiguous 1 KB (perfectly coalesced).
__global__ __launch_bounds__(256, 4) void fused_kernel(const float* __restrict__ O,
                                                       const float* __restrict__ p1,
                                                       const float* __restrict__ p2,
                                                       float* __restrict__ out,
                                                       int nbatch) {
    const int lane = threadIdx.x & 63;
    const int wid = blockIdx.x * (blockDim.x >> 6) + (threadIdx.x >> 6);
    const int nw = gridDim.x * (blockDim.x >> 6);

    // ---- issue first two batches' loads BEFORE the gate chain (overlap)
    int b = wid;
    float4 cur[4], nxt[4];
    const bool has0 = b < nbatch;
    const bool has1 = b + nw < nbatch;
    if (has0) {
        const float4* row = (const float4*)(O + (size_t)b * 1024);
#pragma unroll
        for (int c = 0; c < 4; ++c) cur[c] = row[c * 64 + lane];
    }
    if (has1) {
        const float4* row = (const float4*)(O + (size_t)(b + nw) * 1024);
#pragma unroll
        for (int c = 0; c < 4; ++c) nxt[c] = row[c * 64 + lane];
    }

    // ---- psi1 = U1 @ e0 : forward circuit, params1 (5 blocks, wires 0..4).
    // Lane = basis state (lanes 32..63 mirror 0..31; masks <= 16 never mix halves).
    float p_re = ((lane & 31) == 0) ? 1.f : 0.f, p_im = 0.f;
    for (int bb = 0; bb < 5; ++bb) {
        for (int w = 0; w < 5; ++w) {
            float s, c; __sincosf(p1[bb * 10 + w] * 0.5f, &s, &c);
            apply_ry(c, s, 1 << (4 - w), lane, p_re, p_im);
        }
        for (int w = 0; w < 5; ++w) {
            float s, c; __sincosf(p1[bb * 10 + 5 + w] * 0.5f, &s, &c);
            apply_rx(c, s, 1 << (4 - w), p_re, p_im);
        }
        for (int t = 0; t < 5; ++t)
            if (t != bb) apply_cnot(1 << (4 - bb), 1 << (4 - t), lane, p_re, p_im);
    }
    float r0re, r0im, r1re, r1im;
    u2row(p2, 0, lane, r0re, r0im);
    u2row(p2, 1, lane, r1re, r1im);

    // ---- per-lane coefficient fragments: element e = 256c + 4*lane + k maps
    // to O[i,j], i = e>>5, j = e&31. float4 = {ReW0, ImW0, ReW1, ImW1}.
    float4 cf[4][4];
#pragma unroll
    for (int k = 0; k < 4; ++k) {
        const int e4 = 4 * lane + k;
        const int j = e4 & 31;
        const int tq = e4 >> 5;
        float pr = __shfl(p_re, j, 64);
        float pi = __shfl(p_im, j, 64);
#pragma unroll
        for (int c = 0; c < 4; ++c) {
            const int i = 8 * c + tq;
            float ar = __shfl(r0re, i, 64);
            float ai = __shfl(r0im, i, 64);
            float br = __shfl(r1re, i, 64);
            float bi = __shfl(r1im, i, 64);
            cf[c][k] = make_float4(ar * pr - ai * pi, ar * pi + ai * pr,
                                   br * pr - bi * pi, br * pi + bi * pr);
        }
    }

    if (!has0) return;

    // ---- main streaming loop, software-pipelined (next batch in flight)
    while (true) {
        float a0 = 0.f, a1 = 0.f, a2 = 0.f, a3 = 0.f;
#pragma unroll
        for (int c = 0; c < 4; ++c) {
            float4 o = cur[c];
            a0 += o.x * cf[c][0].x + o.y * cf[c][1].x + o.z * cf[c][2].x + o.w * cf[c][3].x;
            a1 += o.x * cf[c][0].y + o.y * cf[c][1].y + o.z * cf[c][2].y + o.w * cf[c][3].y;
            a2 += o.x * cf[c][0].z + o.y * cf[c][1].z + o.z * cf[c][2].z + o.w * cf[c][3].z;
            a3 += o.x * cf[c][0].w + o.y * cf[c][1].w + o.z * cf[c][2].w + o.w * cf[c][3].w;
        }

        // 9-shuffle reduction: fold 4 accumulators into one value indexed by
        // lane&3, butterfly masks 4..32, then square + 2-shuffle combine.
        float v01 = (lane & 1) ? a1 : a0;
        float o01 = (lane & 1) ? a0 : a1;
        v01 += __shfl_xor(o01, 1, 64);
        float v23 = (lane & 1) ? a3 : a2;
        float o23 = (lane & 1) ? a2 : a3;
        v23 += __shfl_xor(o23, 1, 64);
        float v = (lane & 2) ? v23 : v01;
        float ov = (lane & 2) ? v01 : v23;
        v += __shfl_xor(ov, 2, 64);
#pragma unroll
        for (int m = 4; m < 64; m <<= 1) v += __shfl_xor(v, m, 64);
        float x = v * v;
        x += __shfl_xor(x, 1, 64);
        x += __shfl_xor(x, 2, 64);
        if (lane == 0) ((float2*)out)[b] = make_float2(x, 1.0f - x);

        b += nw;
        if (b >= nbatch) break;
#pragma unroll
        for (int c = 0; c < 4; ++c) cur[c] = nxt[c];
        if (b + nw < nbatch) {
            const float4* row = (const float4*)(O + (size_t)(b + nw) * 1024);
#pragma unroll
            for (int c = 0; c < 4; ++c) nxt[c] = row[c * 64 + lane];
        }
    }
}

extern "C" void kernel_launch(void* const* d_in, const int* in_sizes, int n_in,
                              void* d_out, int out_size, void* d_ws, size_t ws_size,
                              hipStream_t stream) {
    const float* oracles = (const float*)d_in[0];
    const float* p1 = (const float*)d_in[1];
    const float* p2 = (const float*)d_in[2];
    float* out = (float*)d_out;
    int nbatch = in_sizes[0] / 1024;

    // 1024 blocks * 4 waves = 4096 waves: all resident (4 blocks/CU at
    // 4 waves/SIMD), so the redundant circuit sim is paid once, overlapped
    // with the first two batches' prefetch. 16 batches per wave.
    fused_kernel<<<1024, 256, 0, stream>>>(oracles, p1, p2, out, nbatch);
}